// Round 1
// 1179.446 us; speedup vs baseline: 1.2502x; 1.2502x over previous
//
#include <hip/hip_runtime.h>

// Linear4bit: out[M,N] = x[M,K] @ ((q[N,K]-8)*scale[N]->fp16)^T + bias[N]
// M=8192, N=11008, K=4096. fp32 in/out.
// R3: main GEMM moved to the 256x256x64 8-phase counted-vmcnt template
//     (T2 swizzle + T3/T4 counted-vmcnt phases + T5 setprio).
//     Prologues (x->f16, w->f16, bit-exact vs ref) unchanged.
//     Fallbacks kept: 128^2 m97-style kernel (if 128KB LDS attr fails),
//     fused kernel (if ws too small).

#define M_TOK 8192
#define N_OUT 11008
#define K_IN  4096

constexpr int BM = 128, BN = 128, BK = 32;   // legacy fallback tile
constexpr int NBM = M_TOK / BM;   // 64
constexpr int NBN = N_OUT / BN;   // 86

constexpr int NBM2 = M_TOK / 256; // 32
constexpr int NBN2 = N_OUT / 256; // 43
constexpr int NT2  = K_IN / 64;   // 64 K-tiles of BK=64

using h8 = __attribute__((ext_vector_type(8))) _Float16;
using f4 = __attribute__((ext_vector_type(4))) float;

typedef __attribute__((address_space(3))) void       lds_void;
typedef const __attribute__((address_space(1))) void glb_void;

// ---------- prologue 1: x f32 -> f16 ----------
__global__ __launch_bounds__(256)
void cvt_x_f16(const float* __restrict__ x, _Float16* __restrict__ x16) {
    size_t idx = ((size_t)blockIdx.x * 256 + threadIdx.x) * 8;
    float4 a = *(const float4*)(x + idx);
    float4 b = *(const float4*)(x + idx + 4);
    h8 o;
    o[0] = (_Float16)a.x; o[1] = (_Float16)a.y; o[2] = (_Float16)a.z; o[3] = (_Float16)a.w;
    o[4] = (_Float16)b.x; o[5] = (_Float16)b.y; o[6] = (_Float16)b.z; o[7] = (_Float16)b.w;
    *(h8*)(x16 + idx) = o;
}

// ---------- prologue 2: w f16 = fp16((q-8)*scale) ----------
__global__ __launch_bounds__(256)
void cvt_w_f16(const int* __restrict__ qw, const float* __restrict__ scale,
               _Float16* __restrict__ w16) {
    const int row = blockIdx.x;
    const float sc = scale[row];
    const float sb = -8.0f * sc;               // exact (power-of-2 multiple)
    const int*   qp = qw  + (size_t)row * K_IN + threadIdx.x * 16;
    _Float16*    wp = w16 + (size_t)row * K_IN + threadIdx.x * 16;
    int4 q0 = ((const int4*)qp)[0], q1 = ((const int4*)qp)[1];
    int4 q2 = ((const int4*)qp)[2], q3 = ((const int4*)qp)[3];
    int qi[16] = {q0.x,q0.y,q0.z,q0.w, q1.x,q1.y,q1.z,q1.w,
                  q2.x,q2.y,q2.z,q2.w, q3.x,q3.y,q3.z,q3.w};
    h8 lo, hi;
#pragma unroll
    for (int j = 0; j < 8; ++j) {
        lo[j] = (_Float16)fmaf((float)qi[j],     sc, sb);
        hi[j] = (_Float16)fmaf((float)qi[j + 8], sc, sb);
    }
    *(h8*)wp       = lo;
    *(h8*)(wp + 8) = hi;
}

// ---------- 8-phase 256x256x64 GEMM ----------
// LDS map (bytes): buf b @ b*65536; A-half h @ +h*16384; B @ +32768 + h*16384.
// Half = 128 rows x 64 f16 (128 B rows, 8x 16B chunks/row).
// Swizzle: phys_chunk = logical_chunk ^ (row&7), both on stage-source and read.
// Schedule ledger (tile t, phases P0..P3, regions freed by register reuse):
//   reads:  P0: A0(8)+B0(4)  P1: B1(4)  P2: A1(8)  P3: none
//   stages: P0: A1(t+1)->nxt  P1: A0(t+2)->cur  P2: B0(t+2)->cur  P3: B1(t+2)->cur
//   each stage lands >=1 barrier after its region's last ds_read. vmcnt(6) at
//   tile boundary only (3 half-tiles = 6 loads in flight); vmcnt(0) at t=NT-2.
#define BAR()   __builtin_amdgcn_s_barrier()
#define LGKM0() do { asm volatile("s_waitcnt lgkmcnt(0)" ::: "memory"); \
                     __builtin_amdgcn_sched_barrier(0); } while (0)
#define VMCNT(n) asm volatile("s_waitcnt vmcnt(" #n ")" ::: "memory")
#define MFMA16(a, b, c) __builtin_amdgcn_mfma_f32_16x16x32_f16(a, b, c, 0, 0, 0)

#define STAGE_A(buf, h, kofs) do { \
    __builtin_amdgcn_global_load_lds((glb_void*)(gA + (size_t)(h)*128*K_IN + (kofs)), \
        (lds_void*)(ldsAw + (buf)*65536 + (h)*16384), 16, 0, 0); \
    __builtin_amdgcn_global_load_lds((glb_void*)(gA + (size_t)(h)*128*K_IN + 8*K_IN + (kofs)), \
        (lds_void*)(ldsAw + (buf)*65536 + (h)*16384 + 1024), 16, 0, 0); \
} while (0)
#define STAGE_B(buf, h, kofs) do { \
    __builtin_amdgcn_global_load_lds((glb_void*)(gB + (size_t)(h)*128*K_IN + (kofs)), \
        (lds_void*)(ldsBw + (buf)*65536 + (h)*16384), 16, 0, 0); \
    __builtin_amdgcn_global_load_lds((glb_void*)(gB + (size_t)(h)*128*K_IN + 8*K_IN + (kofs)), \
        (lds_void*)(ldsBw + (buf)*65536 + (h)*16384 + 1024), 16, 0, 0); \
} while (0)

#define RD_A(buf, h, fq, kk) \
    (*(const h8*)(smem + (buf)*65536 + (h)*16384 + (fq)*4096 + (aoff ^ ((kk) << 6))))
#define RD_B(buf, g, kk) \
    (*(const h8*)(smem + (buf)*65536 + 32768 + ((g) >> 1)*16384 + ((g)&1)*8192 + (boff ^ ((kk) << 6))))

__global__ __launch_bounds__(512, 2)
void l4b_gemm16_8p(const _Float16* __restrict__ x16, const _Float16* __restrict__ w16,
                   const float* __restrict__ bias, float* __restrict__ out)
{
    extern __shared__ char smem[];              // 131072 B = 2 bufs x (A 32K + B 32K)

    const int tid  = threadIdx.x;
    const int w    = tid >> 6;                  // wave 0..7
    const int lane = tid & 63;
    const int wm   = w & 1;                     // 2 m-waves
    const int wn   = w >> 1;                    // 4 n-waves

    // XCD swizzle: 1376 = 8 * 172 (bijective)
    const int wg = (blockIdx.x & 7) * (NBM2 * NBN2 / 8) + (blockIdx.x >> 3);
    const int bm = wg / NBN2;
    const int bn = wg % NBN2;

    // ---- staging addressing (source pre-swizzled: chunk = (i&7)^(i>>3)) ----
    const int srow   = lane >> 3;                  // 0..7 within 8-row load
    const int schunk = (lane & 7) ^ srow;          // swizzled 16B source chunk
    const _Float16* gA = x16 + (size_t)(bm * 256 + w * 16 + srow) * K_IN + (schunk << 3);
    const _Float16* gB = w16 + (size_t)(bn * 256 + w * 16 + srow) * K_IN + (schunk << 3);
    char* ldsAw = smem + w * 2048;                 // wave-uniform dest bases
    char* ldsBw = smem + 32768 + w * 2048;

    // ---- compute addressing ----
    const int m0   = lane & 15;
    const int quad = lane >> 4;
    const int swz  = (quad ^ (m0 & 7)) << 4;       // kk=0 chunk; kk=1 = ^64
    const int aoff = (wm * 16 + m0) * 128 + swz;
    const int boff = (wn * 16 + m0) * 128 + swz;

    f4 acc[8][4];
#pragma unroll
    for (int f = 0; f < 8; ++f)
#pragma unroll
        for (int g = 0; g < 4; ++g) acc[f][g] = (f4)0.0f;
    h8 afr[4][2], bfr[4][2];

    // ---- prologue: tile0 complete + tile1 {A0,B0,B1}; A1(1) staged in t=0 P0 ----
    STAGE_A(0, 0, 0); STAGE_B(0, 0, 0); STAGE_A(0, 1, 0); STAGE_B(0, 1, 0);
    STAGE_A(1, 0, 64); STAGE_B(1, 0, 64); STAGE_B(1, 1, 64);
    VMCNT(6);                                      // tile0's 8 loads done
    BAR();

#pragma unroll 2
    for (int t = 0; t < NT2; ++t) {
        const int cur = t & 1, nxt = cur ^ 1;
        const int kc = (t + 1) * 64;
        const int kn = (t + 2) * 64;

        // ---- P0: f0-3 x g0-1 ---- reads A-half0 (8) + B-half0 (4)
#pragma unroll
        for (int f = 0; f < 4; ++f) { afr[f][0] = RD_A(cur, 0, f, 0); afr[f][1] = RD_A(cur, 0, f, 1); }
        bfr[0][0] = RD_B(cur, 0, 0); bfr[0][1] = RD_B(cur, 0, 1);
        bfr[1][0] = RD_B(cur, 1, 0); bfr[1][1] = RD_B(cur, 1, 1);
        if (t < NT2 - 1) { STAGE_A(nxt, 1, kc); }  // A1(t+1): nxt.A1 free since t-1's P2
        BAR(); LGKM0();
        __builtin_amdgcn_s_setprio(1);
#pragma unroll
        for (int f = 0; f < 4; ++f)
#pragma unroll
            for (int g = 0; g < 2; ++g) {
                acc[f][g] = MFMA16(afr[f][0], bfr[g][0], acc[f][g]);
                acc[f][g] = MFMA16(afr[f][1], bfr[g][1], acc[f][g]);
            }
        __builtin_amdgcn_s_setprio(0);
        BAR();

        // ---- P1: f0-3 x g2-3 ---- reads B-half1 (4); A regs reused
        bfr[2][0] = RD_B(cur, 2, 0); bfr[2][1] = RD_B(cur, 2, 1);
        bfr[3][0] = RD_B(cur, 3, 0); bfr[3][1] = RD_B(cur, 3, 1);
        if (t < NT2 - 2) { STAGE_A(cur, 0, kn); }  // A0 last read in P0
        BAR(); LGKM0();
        __builtin_amdgcn_s_setprio(1);
#pragma unroll
        for (int f = 0; f < 4; ++f)
#pragma unroll
            for (int g = 2; g < 4; ++g) {
                acc[f][g] = MFMA16(afr[f][0], bfr[g][0], acc[f][g]);
                acc[f][g] = MFMA16(afr[f][1], bfr[g][1], acc[f][g]);
            }
        __builtin_amdgcn_s_setprio(0);
        BAR();

        // ---- P2: f4-7 x g2-3 ---- reads A-half1 (8) into afr (overwrite)
#pragma unroll
        for (int f = 0; f < 4; ++f) { afr[f][0] = RD_A(cur, 1, f, 0); afr[f][1] = RD_A(cur, 1, f, 1); }
        if (t < NT2 - 2) { STAGE_B(cur, 0, kn); }  // B0 last read in P0
        BAR(); LGKM0();
        __builtin_amdgcn_s_setprio(1);
#pragma unroll
        for (int f = 0; f < 4; ++f)
#pragma unroll
            for (int g = 2; g < 4; ++g) {
                acc[4 + f][g] = MFMA16(afr[f][0], bfr[g][0], acc[4 + f][g]);
                acc[4 + f][g] = MFMA16(afr[f][1], bfr[g][1], acc[4 + f][g]);
            }
        __builtin_amdgcn_s_setprio(0);
        BAR();

        // ---- P3: f4-7 x g0-1 ---- no reads (afr half1 + bfr[0,1] reuse)
        if (t < NT2 - 2) { STAGE_B(cur, 1, kn); }  // B1 last read in P1
        BAR(); LGKM0();
        __builtin_amdgcn_s_setprio(1);
#pragma unroll
        for (int f = 0; f < 4; ++f)
#pragma unroll
            for (int g = 0; g < 2; ++g) {
                acc[4 + f][g] = MFMA16(afr[f][0], bfr[g][0], acc[4 + f][g]);
                acc[4 + f][g] = MFMA16(afr[f][1], bfr[g][1], acc[4 + f][g]);
            }
        __builtin_amdgcn_s_setprio(0);
        // ---- tile boundary: counted wait, never 0 in steady state ----
        if (t < NT2 - 2) { VMCNT(6); } else { VMCNT(0); }
        BAR();
    }

    // ---- epilogue: C/D col=lane&15, row=quad*4+reg [verified convention] ----
    const int colb = bn * 256 + wn * 16 + m0;
    const int rowb = bm * 256 + wm * 16 + quad * 4;
    float bv[4];
#pragma unroll
    for (int g = 0; g < 4; ++g) bv[g] = bias[colb + g * 64];
#pragma unroll
    for (int f = 0; f < 8; ++f) {
#pragma unroll
        for (int r = 0; r < 4; ++r) {
            float* op = out + (size_t)(rowb + f * 32 + r) * N_OUT + colb;
#pragma unroll
            for (int g = 0; g < 4; ++g) op[g * 64] = acc[f][g][r] + bv[g];
        }
    }
}

// ---------- legacy 128^2 GEMM (fallback if 128KB LDS attr fails) ----------
__global__ __launch_bounds__(256, 3)
void l4b_gemm16(const _Float16* __restrict__ x16, const _Float16* __restrict__ w16,
                const float* __restrict__ bias, float* __restrict__ out)
{
    __shared__ alignas(16) _Float16 As[BM * BK];
    __shared__ alignas(16) _Float16 Bs[BN * BK];

    const int tid = threadIdx.x;
    const int bid = blockIdx.x;
    const int chunk = bid / (8 * NBN);
    const int rem   = bid % (8 * NBN);
    const int bm    = chunk * 8 + (rem & 7);
    const int bn    = rem >> 3;

    const int wave = tid >> 6;
    const int lane = tid & 63;

    const int r_loc  = lane >> 2;
    const int c_log  = (lane & 3) ^ ((lane >> 3) & 3);
    const _Float16* gA = x16 + (size_t)(bm * BM + wave * 32 + r_loc) * K_IN + (c_log << 3);
    const _Float16* gB = w16 + (size_t)(bn * BN + wave * 32 + r_loc) * K_IN + (c_log << 3);
    _Float16* ldsA = As + wave * 1024;
    _Float16* ldsB = Bs + wave * 1024;

    const int m0   = lane & 15;
    const int quad = lane >> 4;
    const int wm   = (wave & 1) << 6;
    const int wn   = (wave >> 1) << 6;
    const int swq  = (quad ^ ((m0 >> 1) & 3)) << 4;

    f4 acc[4][4];
#pragma unroll
    for (int i = 0; i < 4; ++i)
#pragma unroll
        for (int j = 0; j < 4; ++j)
            acc[i][j] = (f4)0.0f;

    for (int k0 = 0; k0 < K_IN; k0 += BK) {
        __syncthreads();
        __builtin_amdgcn_global_load_lds((glb_void*)(gA + k0),              (lds_void*)ldsA,         16, 0, 0);
        __builtin_amdgcn_global_load_lds((glb_void*)(gA + k0 + 16 * K_IN), (lds_void*)(ldsA + 512), 16, 0, 0);
        __builtin_amdgcn_global_load_lds((glb_void*)(gB + k0),              (lds_void*)ldsB,         16, 0, 0);
        __builtin_amdgcn_global_load_lds((glb_void*)(gB + k0 + 16 * K_IN), (lds_void*)(ldsB + 512), 16, 0, 0);
        __syncthreads();

        h8 af[4], bf[4];
#pragma unroll
        for (int i = 0; i < 4; ++i) {
            af[i] = *(const h8*)((const char*)As + ((wm + (i << 4) + m0) << 6) + swq);
            bf[i] = *(const h8*)((const char*)Bs + ((wn + (i << 4) + m0) << 6) + swq);
        }
#pragma unroll
        for (int i = 0; i < 4; ++i)
#pragma unroll
            for (int j = 0; j < 4; ++j)
                acc[i][j] = __builtin_amdgcn_mfma_f32_16x16x32_f16(
                    af[i], bf[j], acc[i][j], 0, 0, 0);
    }

    const int crow = bm * BM + wm + quad * 4;
    const int ccol = bn * BN + wn + m0;
    float bv[4];
#pragma unroll
    for (int j = 0; j < 4; ++j) bv[j] = bias[ccol + j * 16];

#pragma unroll
    for (int i = 0; i < 4; ++i) {
#pragma unroll
        for (int r = 0; r < 4; ++r) {
            float* op = out + (size_t)(crow + i * 16 + r) * N_OUT + ccol;
#pragma unroll
            for (int j = 0; j < 4; ++j)
                op[j * 16] = acc[i][j][r] + bv[j];
        }
    }
}

// ---------- fallback (R1 fused kernel) if ws is too small ----------
constexpr int LDK = BK + 8;
__global__ __launch_bounds__(256, 2)
void l4b_fused_gemm(const float* __restrict__ x,
                    const int*   __restrict__ qw,
                    const float* __restrict__ scale,
                    const float* __restrict__ bias,
                    float*       __restrict__ out)
{
    __shared__ alignas(16) _Float16 As[BM][LDK];
    __shared__ alignas(16) _Float16 Bs[BN][LDK];

    const int tid = threadIdx.x;
    const int bid = blockIdx.x;
    const int chunk = bid / (8 * NBN);
    const int rem   = bid % (8 * NBN);
    const int bm    = chunk * 8 + (rem & 7);
    const int bn    = rem >> 3;

    const int row  = tid >> 1;
    const int kseg = (tid & 1) << 4;

    const float* xp = x  + (size_t)(bm * BM + row) * K_IN + kseg;
    const int*   qp = qw + (size_t)(bn * BN + row) * K_IN + kseg;
    const float  sc = scale[bn * BN + row];
    const float  sb = -8.0f * sc;

    const int wave = tid >> 6;
    const int lane = tid & 63;
    const int wm   = (wave & 1) << 6;
    const int wn   = (wave >> 1) << 6;
    const int m0   = lane & 15;
    const int quad = lane >> 4;
    const int kq   = quad << 3;

    f4 acc[4][4];
#pragma unroll
    for (int i = 0; i < 4; ++i)
#pragma unroll
        for (int j = 0; j < 4; ++j)
            acc[i][j] = (f4)0.0f;

    for (int k0 = 0; k0 < K_IN; k0 += BK) {
        const float4* xv = (const float4*)(xp + k0);
        const int4*   qv = (const int4*)(qp + k0);
        float4 a0 = xv[0], a1 = xv[1], a2 = xv[2], a3 = xv[3];
        int4   q0 = qv[0], q1 = qv[1], q2 = qv[2], q3 = qv[3];
        float af[16] = {a0.x,a0.y,a0.z,a0.w, a1.x,a1.y,a1.z,a1.w,
                        a2.x,a2.y,a2.z,a2.w, a3.x,a3.y,a3.z,a3.w};
        int   qi[16] = {q0.x,q0.y,q0.z,q0.w, q1.x,q1.y,q1.z,q1.w,
                        q2.x,q2.y,q2.z,q2.w, q3.x,q3.y,q3.z,q3.w};
        h8 alo, ahi, blo, bhi;
#pragma unroll
        for (int i = 0; i < 8; ++i) {
            alo[i] = (_Float16)af[i];
            ahi[i] = (_Float16)af[i + 8];
            blo[i] = (_Float16)fmaf((float)qi[i],     sc, sb);
            bhi[i] = (_Float16)fmaf((float)qi[i + 8], sc, sb);
        }
        __syncthreads();
        *(h8*)&As[row][kseg]     = alo;
        *(h8*)&As[row][kseg + 8] = ahi;
        *(h8*)&Bs[row][kseg]     = blo;
        *(h8*)&Bs[row][kseg + 8] = bhi;
        __syncthreads();
        h8 afr[4], bfr[4];
#pragma unroll
        for (int i = 0; i < 4; ++i) {
            afr[i] = *(const h8*)&As[wm + i * 16 + m0][kq];
            bfr[i] = *(const h8*)&Bs[wn + i * 16 + m0][kq];
        }
#pragma unroll
        for (int i = 0; i < 4; ++i)
#pragma unroll
            for (int j = 0; j < 4; ++j)
                acc[i][j] = __builtin_amdgcn_mfma_f32_16x16x32_f16(
                    afr[i], bfr[j], acc[i][j], 0, 0, 0);
    }

    const int crow = bm * BM + wm + quad * 4;
    const int ccol = bn * BN + wn + m0;
    float bv[4];
#pragma unroll
    for (int j = 0; j < 4; ++j) bv[j] = bias[ccol + j * 16];
#pragma unroll
    for (int i = 0; i < 4; ++i)
#pragma unroll
        for (int r = 0; r < 4; ++r) {
            float* op = out + (size_t)(crow + i * 16 + r) * N_OUT + ccol;
#pragma unroll
            for (int j = 0; j < 4; ++j)
                op[j * 16] = acc[i][j][r] + bv[j];
        }
}

extern "C" void kernel_launch(void* const* d_in, const int* in_sizes, int n_in,
                              void* d_out, int out_size, void* d_ws, size_t ws_size,
                              hipStream_t stream) {
    const float* x     = (const float*)d_in[0];
    const int*   qw    = (const int*)d_in[1];
    const float* scale = (const float*)d_in[2];
    const float* bias  = (const float*)d_in[3];
    float*       out   = (float*)d_out;

    const size_t x16_bytes = (size_t)M_TOK * K_IN * 2;
    const size_t w16_bytes = (size_t)N_OUT * K_IN * 2;
    if (ws_size >= x16_bytes + w16_bytes) {
        _Float16* x16 = (_Float16*)d_ws;
        _Float16* w16 = (_Float16*)((char*)d_ws + x16_bytes);
        cvt_x_f16<<<dim3((M_TOK * K_IN) / (256 * 8)), dim3(256), 0, stream>>>(x, x16);
        cvt_w_f16<<<dim3(N_OUT), dim3(256), 0, stream>>>(qw, scale, w16);

        static int smem_ok = -1;
        if (smem_ok < 0) {
            hipError_t e = hipFuncSetAttribute(
                reinterpret_cast<const void*>(l4b_gemm16_8p),
                hipFuncAttributeMaxDynamicSharedMemorySize, 131072);
            smem_ok = (e == hipSuccess) ? 1 : 0;
        }
        if (smem_ok == 1) {
            l4b_gemm16_8p<<<dim3(NBM2 * NBN2), dim3(512), 131072, stream>>>(x16, w16, bias, out);
        } else {
            l4b_gemm16<<<dim3(NBM * NBN), dim3(256), 0, stream>>>(x16, w16, bias, out);
        }
    } else {
        l4b_fused_gemm<<<dim3(NBM * NBN), dim3(256), 0, stream>>>(x, qw, scale, bias, out);
    }
}